// Round 1
// baseline (13.415 us; speedup 1.0000x reference)
//
#include <hip/hip_runtime.h>

// RTL (random tiny lattice) layer:
//   x: (2048, 128) f32, kernel: (81, 1024) f32, indices: (1024, 4) i32
//   out[b,l] = sum_v prod_r hat(x[b, idx[l,r]] - digit_r(v)) * kernel[v,l]
// Hat basis with unit spacing => 16-point multilinear interp per output.

#define BATCH   2048
#define NFEAT   128
#define NLAT    1024
#define NVERT   81
#define LT      128   // lattices per block
#define BT      32    // batch rows per block
#define THREADS 256

__global__ __launch_bounds__(THREADS, 2)
void rtl_kernel(const float* __restrict__ x,
                const float* __restrict__ kern,
                const int*   __restrict__ indices,
                float*       __restrict__ out) {
    // LDS: kernel slice [81][128] (41472 B) + x tile [32][128] (16384 B)
    __shared__ float Klds[NVERT * LT];
    __shared__ float Xlds[BT * NFEAT];

    const int tid   = threadIdx.x;
    const int ltile = blockIdx.x & (NLAT / LT - 1);  // 8 lattice tiles
    const int btile = blockIdx.x >> 3;               // 64 batch tiles
    const int l0    = ltile * LT;
    const int b0    = btile * BT;

    // Stage kernel slice: 81 rows of 128 floats = 2592 float4
    {
        float4* dst4 = (float4*)Klds;
        for (int i = tid; i < NVERT * (LT / 4); i += THREADS) {
            const int v = i >> 5;     // row (vertex)
            const int c = i & 31;     // float4 col within row
            dst4[i] = *(const float4*)(kern + v * NLAT + l0 + c * 4);
        }
    }
    // Stage x tile: 32*128 = 4096 floats = 1024 float4 (fully coalesced)
    {
        float4* dst4 = (float4*)Xlds;
        const float4* src4 = (const float4*)(x + b0 * NFEAT);
        for (int i = tid; i < (BT * NFEAT) / 4; i += THREADS) {
            dst4[i] = src4[i];
        }
    }

    // Per-thread fixed lattice; two batch-row groups (tid>>7 in {0,1})
    const int ll   = tid & (LT - 1);
    const int bsub = tid >> 7;
    const int4 idx = *(const int4*)(indices + (l0 + ll) * 4);

    __syncthreads();

    const float* kbase = Klds + ll;

    for (int bi = bsub; bi < BT; bi += THREADS / LT) {
        const float* xr = Xlds + bi * NFEAT;
        float x0 = xr[idx.x];
        float x1 = xr[idx.y];
        float x2 = xr[idx.z];
        float x3 = xr[idx.w];
        // clip to [0, 2]
        x0 = fminf(fmaxf(x0, 0.0f), 2.0f);
        x1 = fminf(fmaxf(x1, 0.0f), 2.0f);
        x2 = fminf(fmaxf(x2, 0.0f), 2.0f);
        x3 = fminf(fmaxf(x3, 0.0f), 2.0f);
        // cell index (clamped so i+1 <= 2) and fractional coordinate
        const int i0 = min((int)x0, 1); const float t0 = x0 - (float)i0;
        const int i1 = min((int)x1, 1); const float t1 = x1 - (float)i1;
        const int i2 = min((int)x2, 1); const float t2 = x2 - (float)i2;
        const int i3 = min((int)x3, 1); const float t3 = x3 - (float)i3;

        const int vb = ((i0 * 3 + i1) * 3 + i2) * 3 + i3;   // base vertex
        const float* kp = kbase + vb * LT;

        // 16 gathers + multilinear interp (lerp tree over dims 3,2,1,0).
        // LDS addr = (vb + delta)*128 + ll: bank = ll%32 always -> conflict-free.
        float a3[8];
#pragma unroll
        for (int c = 0; c < 8; ++c) {
            const int d = ((c >> 2) & 1) * 27 + ((c >> 1) & 1) * 9 + (c & 1) * 3;
            const float lo = kp[d * LT];
            const float hi = kp[(d + 1) * LT];
            a3[c] = fmaf(t3, hi - lo, lo);
        }
        float a2[4];
#pragma unroll
        for (int j = 0; j < 4; ++j) {
            a2[j] = fmaf(t2, a3[2 * j + 1] - a3[2 * j], a3[2 * j]);
        }
        const float n0 = fmaf(t1, a2[1] - a2[0], a2[0]);
        const float n1 = fmaf(t1, a2[3] - a2[2], a2[2]);
        const float res = fmaf(t0, n1 - n0, n0);

        out[(b0 + bi) * NLAT + l0 + ll] = res;
    }
}

extern "C" void kernel_launch(void* const* d_in, const int* in_sizes, int n_in,
                              void* d_out, int out_size, void* d_ws, size_t ws_size,
                              hipStream_t stream) {
    const float* x       = (const float*)d_in[0];
    const float* kern    = (const float*)d_in[1];
    const int*   indices = (const int*)d_in[2];
    float*       out     = (float*)d_out;

    const int grid = (NLAT / LT) * (BATCH / BT);  // 8 * 64 = 512 blocks
    rtl_kernel<<<grid, THREADS, 0, stream>>>(x, kern, indices, out);
}